// Round 15
// baseline (559.524 us; speedup 1.0000x reference)
//
#include <hip/hip_runtime.h>
#include <hip/hip_bf16.h>
#include <cstdint>
#include <cstddef>

#define D_ 1024
#define H_ 4096
#define E_ 16
#define B_ 2048

constexpr int CAP = 512;   // per-expert slot capacity (mean 256; 320-row tile + guard)

typedef __attribute__((ext_vector_type(4))) float f32x4;
typedef __attribute__((ext_vector_type(8))) short bf16x8;

__device__ __forceinline__ unsigned pack2(float a, float b) {
  __hip_bfloat162 h = __float22bfloat162_rn(make_float2(a, b));
  union { __hip_bfloat162 h2; unsigned u; } cv; cv.h2 = h;
  return cv.u;   // a lo16, b hi16 (v_cvt_pk_bf16_f32, RNE)
}
__device__ __forceinline__ float bflo(unsigned u) { return __uint_as_float(u << 16); }
__device__ __forceinline__ float bfhi(unsigned u) { return __uint_as_float(u & 0xffff0000u); }

#define GLL16(g, l)                                                         \
  __builtin_amdgcn_global_load_lds(                                         \
      (const __attribute__((address_space(1))) void*)(g),                   \
      (__attribute__((address_space(3))) void*)(l), 16, 0, 0)

#define WAITV(n) asm volatile("s_waitcnt vmcnt(" #n ")" ::: "memory")
#define WAITL()  asm volatile("s_waitcnt lgkmcnt(0)" ::: "memory")
#define MEMBAR() asm volatile("" ::: "memory")
#define BAR() __builtin_amdgcn_s_barrier()

// ================= tiny: zero the expert counters =================
__global__ void moe_zero(int* __restrict__ cnt) {
  if (threadIdx.x < E_) cnt[threadIdx.x] = 0;
}

// ================= gating: LN(x)@norm(keys) -> top2 -> rmeta + bf16 X gather =================
__global__ __launch_bounds__(256) void moe_gating3(
    const float* __restrict__ x, const float* __restrict__ gamma,
    const float* __restrict__ beta, const float* __restrict__ keys,
    int* __restrict__ cnt, int4* __restrict__ rmi, float2* __restrict__ rmg,
    unsigned short* __restrict__ xg)
{
  const int b = blockIdx.x, t = threadIdx.x;
  const int w = t >> 6;
  const float4 xv = ((const float4*)(x + (size_t)b * D_))[t];  // d = 4t..4t+3
  float s  = xv.x + xv.y + xv.z + xv.w;
  float sq = xv.x*xv.x + xv.y*xv.y + xv.z*xv.z + xv.w*xv.w;
#pragma unroll
  for (int off = 32; off >= 1; off >>= 1) {
    s  += __shfl_down(s, off);
    sq += __shfl_down(sq, off);
  }
  __shared__ float ssum[4], ssq[4], sstat[2];
  if ((t & 63) == 0) { ssum[w] = s; ssq[w] = sq; }
  __syncthreads();
  if (t == 0) {
    float S = ssum[0] + ssum[1] + ssum[2] + ssum[3];
    float Q = ssq[0] + ssq[1] + ssq[2] + ssq[3];
    float mu  = S * (1.0f / D_);
    float var = Q * (1.0f / D_) - mu * mu;
    sstat[0] = mu; sstat[1] = rsqrtf(var + 1e-5f);
  }
  __syncthreads();
  const float mu = sstat[0], rstd = sstat[1];
  const float4 gv = ((const float4*)gamma)[t];
  const float4 bv = ((const float4*)beta)[t];
  float xn[4] = {(xv.x-mu)*rstd*gv.x+bv.x, (xv.y-mu)*rstd*gv.y+bv.y,
                 (xv.z-mu)*rstd*gv.z+bv.z, (xv.w-mu)*rstd*gv.w+bv.w};
  float acc[E_];
#pragma unroll
  for (int e2 = 0; e2 < E_; ++e2) acc[e2] = 0.f;
#pragma unroll
  for (int j = 0; j < 4; ++j) {
    const int d = 4*t + j;
    const float* kr = keys + (size_t)d * E_;
    float kv[E_];
#pragma unroll
    for (int e2 = 0; e2 < E_; ++e2) kv[e2] = kr[e2];
    float nq = 0.f;
#pragma unroll
    for (int e2 = 0; e2 < E_; ++e2) nq += kv[e2] * kv[e2];
    const float sc = xn[j] / fmaxf(sqrtf(nq), 1e-12f);
#pragma unroll
    for (int e2 = 0; e2 < E_; ++e2) acc[e2] += sc * kv[e2];
  }
#pragma unroll
  for (int off = 1; off < 64; off <<= 1) {
#pragma unroll
    for (int e2 = 0; e2 < E_; ++e2) acc[e2] += __shfl_xor(acc[e2], off);
  }
  __shared__ float wred[4][E_];
  if ((t & 63) == 0) {
#pragma unroll
    for (int e2 = 0; e2 < E_; ++e2) wred[w][e2] = acc[e2];
  }
  __syncthreads();
  __shared__ int sE[2], sP[2];
  if (t == 0) {
    float lg[E_];
#pragma unroll
    for (int e2 = 0; e2 < E_; ++e2)
      lg[e2] = wred[0][e2] + wred[1][e2] + wred[2][e2] + wred[3][e2];
    float v0 = -1e30f; int e0 = 0;
    for (int e2 = 0; e2 < E_; ++e2) { if (lg[e2] > v0) { v0 = lg[e2]; e0 = e2; } }
    float v1 = -1e30f; int e1 = 0;
    for (int e2 = 0; e2 < E_; ++e2) { if (e2 == e0) continue; if (lg[e2] > v1) { v1 = lg[e2]; e1 = e2; } }
    const float g0 = 1.f / (1.f + __expf(v1 - v0));
    const float g1 = 1.f - g0;
    int p0 = atomicAdd(cnt + e0, 1); if (p0 >= CAP) p0 = CAP - 1;
    int p1 = atomicAdd(cnt + e1, 1); if (p1 >= CAP) p1 = CAP - 1;
    rmi[b] = make_int4(e0, p0, e1, p1);
    rmg[b] = make_float2(g0, g1);
    sE[0] = e0; sP[0] = p0;
    sE[1] = e1; sP[1] = p1;
  }
  __syncthreads();
  const uint2 pk = make_uint2(pack2(xv.x, xv.y), pack2(xv.z, xv.w));
#pragma unroll
  for (int i = 0; i < 2; ++i)
    ((uint2*)(xg + ((size_t)sE[i] * CAP + sP[i]) * D_))[t] = pk;
}

// ================= grouped GEMM: dst = [relu](A @ W [+ bias]) -> bf16 =================
// Pareto tiling under the measured ~5 TB/s delivered-byte rate:
// bytes/expert = NT*A_slab + MT*W_slab -> maximize tile dims. Tile 320 x 128,
// 512 thr / 8 waves (2 row x 4 col), acc = 80 f32/thread, MT=1 (+guard tile,
// early-returns unless cnt > 320). Kstep=32, NBUF=2, LDS 56 KiB -> 2 blocks/CU.
// A bf16 via global_load_lds: 2 full rounds + 1 conditional round (t<256,
// wave-uniform); chunk-XOR source swizzle -> conflict-free b128 reads.
// B fp32: 8 coalesced dwords/thread -> cvt_pk -> one b128 ds_write into pad-free
// [n][32k] bf16 LDS with chunk-XOR (0 conflicts, proven). 2-phase-deep B.
// Ledger at WAITV(8): keeps exactly the youngest B-batch (both wave classes).
template<int KROW, int KLEN, int WN, int SPLITK, bool RELU>
__global__ void __launch_bounds__(512, 2)
moe_gemm(const unsigned short* __restrict__ Asrc, const float* __restrict__ W,
         const float* __restrict__ bias, const int* __restrict__ cnt,
         unsigned short* __restrict__ d0, unsigned short* __restrict__ d1,
         unsigned short* __restrict__ d2, unsigned short* __restrict__ d3)
{
  constexpr int NPHASE = KLEN / 32;   // even
  constexpr int NT = WN / 128;        // N-strips per expert per part

  const int bx = blockIdx.x;
  const int xcd = bx & 7;
  int slot = bx >> 3;
  const int mt = slot & 1;  slot >>= 1;          // guard tile (rows 320..cnt), rare
  const int nt = slot % NT; slot /= NT;
  const int eh = slot & 1;  slot >>= 1;
  const int part = slot;                          // 0..SPLITK-1
  const int e  = (xcd << 1) | eh;                 // 2 experts per XCD
  const int nb = nt * 128;
  const int koff = part * KLEN;
  unsigned short* dst = (part == 0) ? d0 : (part == 1) ? d1 : (part == 2) ? d2 : d3;

  int cntE = cnt[e]; if (cntE > CAP) cntE = CAP;
  if (mt * 320 >= cntE) return;      // guard tile almost always returns

  const int t = threadIdx.x, w = t >> 6, lane = t & 63;
  const int l15 = lane & 15, l4 = lane >> 4;
  const int wr = w >> 2, wc = w & 3;  // 2 row-waves (160 rows) x 4 col-waves (32 cols)

  __shared__ __align__(16) unsigned short As[2][320 * 32];   // 20 KiB each
  __shared__ __align__(16) unsigned short Bs[2][128 * 32];   // 8 KiB each (pad-free)

  asm volatile("s_waitcnt vmcnt(0) lgkmcnt(0)" ::: "memory");

  const unsigned short* Ae = Asrc + (size_t)e * CAP * KROW + (size_t)mt * 320 * KROW + koff;
  const float* We = W + (size_t)e * KROW * WN + (size_t)koff * WN + nb;

  // A staging: chunk c = i*512+t (i=0,1) + conditional c=1024+t (t<256);
  // row = c>>2 (0..319); src chunk = (c&3)^((row>>1)&3)
  const unsigned short *srcA0, *srcA1, *srcA2;
  {
    const int c0 = t,         r0 = c0 >> 2;
    const int c1 = t + 512,   r1 = c1 >> 2;
    const int c2 = t + 1024,  r2 = c2 >> 2;     // only t<256 uses this
    srcA0 = Ae + (size_t)r0 * KROW + ((c0 & 3) ^ ((r0 >> 1) & 3)) * 8;
    srcA1 = Ae + (size_t)r1 * KROW + ((c1 & 3) ^ ((r1 >> 1) & 3)) * 8;
    srcA2 = Ae + (size_t)r2 * KROW + ((c2 & 3) ^ ((r2 >> 1) & 3)) * 8;
  }
  // B load: thread t -> col bn = t&127, k-quarter bkq = t>>7 (rows bkq*8..bkq*8+7)
  const int bn = t & 127, bkq = t >> 7;
  const float* srcB = We + (size_t)(bkq * 8) * WN + bn;
  // B LDS write offset: pad-free [n][32k] bf16; chunk bkq, phys chunk ^= (n>>1)&3
  const int bo = bn * 64 + ((bkq ^ ((bn >> 1) & 3)) << 4);

  float R0[8], R1[8];   // two B reg buffers (static indexing only)

#define ISSUE_A(p, BUF) do {                                                \
    const int ko_ = (p) * 32;                                               \
    GLL16(srcA0 + ko_, &As[BUF][(0 * 512 + w * 64) * 8]);                   \
    GLL16(srcA1 + ko_, &As[BUF][(1 * 512 + w * 64) * 8]);                   \
    if (t < 256) GLL16(srcA2 + ko_, &As[BUF][(1024 + w * 64) * 8]);         \
  } while (0)

#define ISSUE_B(p, Rv) do {                                                 \
    const float* bp_ = srcB + (size_t)(p) * 32 * WN;                        \
    _Pragma("unroll")                                                       \
    for (int j = 0; j < 8; ++j)                                             \
      Rv[j] = bp_[(size_t)j * WN];                                          \
  } while (0)

#define WRITE(Rv, BUF) do {                                                 \
    uint4 q_;                                                               \
    q_.x = pack2(Rv[0], Rv[1]);  q_.y = pack2(Rv[2], Rv[3]);                \
    q_.z = pack2(Rv[4], Rv[5]);  q_.w = pack2(Rv[6], Rv[7]);                \
    *(uint4*)((char*)&Bs[BUF][0] + bo) = q_;                                \
  } while (0)

  f32x4 acc[10][2];
#pragma unroll
  for (int rf = 0; rf < 10; ++rf) { acc[rf][0] = f32x4{0,0,0,0}; acc[rf][1] = f32x4{0,0,0,0}; }

  const int swA = (l15 >> 1) & 3;             // A-read chunk XOR
  const int mrow0 = mt * 320;
  const int wrow = wr * 160;                  // wave's 160-row band

#define COMP(BUF) do {                                                      \
    __builtin_amdgcn_s_setprio(1);                                          \
    _Pragma("unroll")                                                       \
    for (int cf = 0; cf < 2; ++cf) {                                        \
      const int n_ = wc * 32 + cf * 16 + l15;                               \
      const bf16x8 bb = *(const bf16x8*)((const char*)&Bs[BUF][0]           \
               + (n_ * 64 + ((l4 ^ ((n_ >> 1) & 3)) << 4)));                \
      _Pragma("unroll")                                                     \
      for (int rf = 0; rf < 10; ++rf) {                                     \
        if (mrow0 + wrow + rf * 16 < cntE) {                                \
          const bf16x8 a = *(const bf16x8*)&As[BUF][((wrow + rf * 16 + l15) * 4 + (l4 ^ swA)) * 8]; \
          acc[rf][cf] = __builtin_amdgcn_mfma_f32_16x16x32_bf16(a, bb, acc[rf][cf], 0,0,0); \
        }                                                                   \
      }                                                                     \
    }                                                                       \
    __builtin_amdgcn_s_setprio(0);                                          \
  } while (0)

  // prologue: FIFO order A(0) | B(0) | B(1)
  ISSUE_A(0, 0); MEMBAR();
  ISSUE_B(0, R0); MEMBAR();
  ISSUE_B(1, R1);
#pragma unroll 1
  for (int p = 0; p < NPHASE; p += 2) {
    // ---- phase p: bufs 0, B regs R0
    if (p + 1 < NPHASE) { WAITV(8); } else { WAITV(0); }
    WRITE(R0, 0);
    if (p + 1 < NPHASE) { ISSUE_A(p + 1, 1); }
    MEMBAR();
    if (p + 2 < NPHASE) { ISSUE_B(p + 2, R0); }
    WAITL(); BAR();
    COMP(0);
    BAR();
    // ---- phase p+1: bufs 1, B regs R1
    if (p + 1 < NPHASE) {
      if (p + 2 < NPHASE) { WAITV(8); } else { WAITV(0); }
      WRITE(R1, 1);
      if (p + 2 < NPHASE) { ISSUE_A(p + 2, 0); }
      MEMBAR();
      if (p + 3 < NPHASE) { ISSUE_B(p + 3, R1); }
      WAITL(); BAR();
      COMP(1);
      BAR();
    }
  }
#undef ISSUE_A
#undef ISSUE_B
#undef WRITE
#undef COMP

  // epilogue: [relu(acc+bias)] -> dst bf16, 4-col packs via shfl
  unsigned short* dbase = dst + (size_t)e * CAP * WN + nb + wc * 32;
#pragma unroll
  for (int rf = 0; rf < 10; ++rf) {
    if (mrow0 + wrow + rf * 16 >= cntE) continue;      // wave-uniform skip
#pragma unroll
    for (int cf = 0; cf < 2; ++cf) {
      float bv = 0.f;
      if constexpr (RELU) bv = bias[e * WN + nb + wc * 32 + cf * 16 + l15];
#pragma unroll
      for (int r = 0; r < 4; ++r) {
        const int row = mrow0 + wrow + rf * 16 + l4 * 4 + r;
        float v = acc[rf][cf][r];
        if constexpr (RELU) v = fmaxf(v + bv, 0.f);
        const unsigned u01 = pack2(v, __shfl_xor(v, 1));
        const float uo = __shfl_xor(__uint_as_float(u01), 2);
        if ((l15 & 3) == 0)
          *(uint2*)(dbase + (size_t)row * WN + cf * 16 + l15) =
              make_uint2(u01, __float_as_uint(uo));
      }
    }
  }
}

// ================= combine: out[b] = g0*(sum eoP[e0]+b2) + g1*(sum eoP[e1]+b2) ============
__global__ __launch_bounds__(256) void moe_comb(
    const unsigned short* __restrict__ p0, const unsigned short* __restrict__ p1,
    const unsigned short* __restrict__ p2, const unsigned short* __restrict__ p3,
    const float* __restrict__ b2, const int4* __restrict__ rmi,
    const float2* __restrict__ rmg, float* __restrict__ out)
{
  const int b = blockIdx.x, t = threadIdx.x;
  const int4 m = rmi[b];
  const float2 g = rmg[b];
  const int c = t * 4;
  const size_t offA = ((size_t)m.x * CAP + m.y) * D_ + c;
  const size_t offB = ((size_t)m.z * CAP + m.w) * D_ + c;
  float a0, a1, a2, a3, c0, c1, c2, c3;
  {
    const uint2 ua = *(const uint2*)(p0 + offA);
    const uint2 ub = *(const uint2*)(p0 + offB);
    a0 = bflo(ua.x); a1 = bfhi(ua.x); a2 = bflo(ua.y); a3 = bfhi(ua.y);
    c0 = bflo(ub.x); c1 = bfhi(ub.x); c2 = bflo(ub.y); c3 = bfhi(ub.y);
  }
  const unsigned short* parts[3] = { p1, p2, p3 };
#pragma unroll
  for (int i = 0; i < 3; ++i) {
    if (parts[i] != nullptr) {
      const uint2 ua = *(const uint2*)(parts[i] + offA);
      const uint2 ub = *(const uint2*)(parts[i] + offB);
      a0 += bflo(ua.x); a1 += bfhi(ua.x); a2 += bflo(ua.y); a3 += bfhi(ua.y);
      c0 += bflo(ub.x); c1 += bfhi(ub.x); c2 += bflo(ub.y); c3 += bfhi(ub.y);
    }
  }
  const float4 b2a = *(const float4*)(b2 + (size_t)m.x * D_ + c);
  const float4 b2b = *(const float4*)(b2 + (size_t)m.z * D_ + c);
  float4 o;
  o.x = g.x * (a0 + b2a.x) + g.y * (c0 + b2b.x);
  o.y = g.x * (a1 + b2a.y) + g.y * (c1 + b2b.y);
  o.z = g.x * (a2 + b2a.z) + g.y * (c2 + b2b.z);
  o.w = g.x * (a3 + b2a.w) + g.y * (c3 + b2b.w);
  *(float4*)(out + (size_t)b * D_ + c) = o;
}

// ======================= launch =======================
extern "C" void kernel_launch(void* const* d_in, const int* in_sizes, int n_in,
                              void* d_out, int out_size, void* d_ws, size_t ws_size,
                              hipStream_t stream) {
  const float* x     = (const float*)d_in[0];
  const float* gamma = (const float*)d_in[1];
  const float* beta  = (const float*)d_in[2];
  const float* keys  = (const float*)d_in[3];
  const float* W1    = (const float*)d_in[4];
  const float* b1    = (const float*)d_in[5];
  const float* W2    = (const float*)d_in[6];
  const float* b2    = (const float*)d_in[7];
  float* out = (float*)d_out;

  char* ws = (char*)d_ws;
  const size_t OFF_RMI = 256;
  const size_t OFF_RMG = OFF_RMI + (size_t)B_ * 16;
  const size_t OFF_XG  = OFF_RMG + (size_t)B_ * 8;
  const size_t EO_SZ   = (size_t)E_ * CAP * D_ * 2;            // 16 MiB
  const size_t OFF_HW  = OFF_XG + EO_SZ;                       // xg / eo part0 overlay
  const size_t HW_SZ   = (size_t)E_ * CAP * H_ * 2;            // 64 MiB
  const size_t OFF_EO1 = OFF_HW + HW_SZ;
  const size_t NEED2   = OFF_EO1 + EO_SZ;                      // ~96 MiB
  const size_t NEED4   = OFF_EO1 + 3 * EO_SZ;                  // ~128 MiB (ws ~1 GiB measured)

  int*    cnt = (int*)ws;
  int4*   rmi = (int4*)(ws + OFF_RMI);
  float2* rmg = (float2*)(ws + OFF_RMG);
  unsigned short* xg  = (unsigned short*)(ws + OFF_XG);
  unsigned short* eo0 = xg;                                    // xg dead after GEMM1
  unsigned short* hws = (unsigned short*)(ws + OFF_HW);

  moe_zero<<<1, 64, 0, stream>>>(cnt);
  moe_gating3<<<B_, 256, 0, stream>>>(x, gamma, beta, keys, cnt, rmi, rmg, xg);

  // GEMM1: tile 320x128, grid 1024 (8 xcd x 2 mt x 32 nt x 2 eh), 2 blocks/CU
  moe_gemm<D_, D_, H_, 1, true><<<1024, 512, 0, stream>>>(
      xg, W1, b1, cnt, hws, nullptr, nullptr, nullptr);

  if (ws_size >= NEED4) {
    // GEMM2: tile 320x128, split-K=4, grid 1024 (8 x 2 mt x 8 nt x 2 eh x 4 part)
    unsigned short* eo1 = (unsigned short*)(ws + OFF_EO1);
    unsigned short* eo2 = (unsigned short*)(ws + OFF_EO1 + EO_SZ);
    unsigned short* eo3 = (unsigned short*)(ws + OFF_EO1 + 2 * EO_SZ);
    moe_gemm<H_, H_ / 4, D_, 4, false><<<1024, 512, 0, stream>>>(
        hws, W2, nullptr, cnt, eo0, eo1, eo2, eo3);
    moe_comb<<<B_, 256, 0, stream>>>(eo0, eo1, eo2, eo3, b2, rmi, rmg, out);
  } else if (ws_size >= NEED2) {
    // GEMM2: split-K=2, grid 512
    unsigned short* eo1 = (unsigned short*)(ws + OFF_EO1);
    moe_gemm<H_, H_ / 2, D_, 2, false><<<512, 512, 0, stream>>>(
        hws, W2, nullptr, cnt, eo0, eo1, nullptr, nullptr);
    moe_comb<<<B_, 256, 0, stream>>>(eo0, eo1, nullptr, nullptr, b2, rmi, rmg, out);
  } else {
    // GEMM2: no split, grid 256
    moe_gemm<H_, H_, D_, 1, false><<<256, 512, 0, stream>>>(
        hws, W2, nullptr, cnt, eo0, nullptr, nullptr, nullptr);
    moe_comb<<<B_, 256, 0, stream>>>(eo0, nullptr, nullptr, nullptr, b2, rmi, rmg, out);
  }
}

// Round 16
// 288.653 us; speedup vs baseline: 1.9384x; 1.9384x over previous
//
#include <hip/hip_runtime.h>
#include <hip/hip_bf16.h>
#include <cstdint>
#include <cstddef>

#define D_ 1024
#define H_ 4096
#define E_ 16
#define B_ 2048

constexpr int CAP = 384;   // per-expert slot capacity (mean 256, ~8 sigma)

typedef __attribute__((ext_vector_type(4))) float f32x4;
typedef __attribute__((ext_vector_type(8))) short bf16x8;

__device__ __forceinline__ unsigned pack2(float a, float b) {
  __hip_bfloat162 h = __float22bfloat162_rn(make_float2(a, b));
  union { __hip_bfloat162 h2; unsigned u; } cv; cv.h2 = h;
  return cv.u;   // a lo16, b hi16 (v_cvt_pk_bf16_f32, RNE)
}
__device__ __forceinline__ float bflo(unsigned u) { return __uint_as_float(u << 16); }
__device__ __forceinline__ float bfhi(unsigned u) { return __uint_as_float(u & 0xffff0000u); }

#define GLL16(g, l)                                                         \
  __builtin_amdgcn_global_load_lds(                                         \
      (const __attribute__((address_space(1))) void*)(g),                   \
      (__attribute__((address_space(3))) void*)(l), 16, 0, 0)

#define WAITV(n) asm volatile("s_waitcnt vmcnt(" #n ")" ::: "memory")
#define WAITL()  asm volatile("s_waitcnt lgkmcnt(0)" ::: "memory")
#define MEMBAR() asm volatile("" ::: "memory")
#define BAR() __builtin_amdgcn_s_barrier()

// ================= tiny: zero the expert counters =================
__global__ void moe_zero(int* __restrict__ cnt) {
  if (threadIdx.x < E_) cnt[threadIdx.x] = 0;
}

// ================= gating: LN(x)@norm(keys) -> top2 -> rmeta + bf16 X gather =================
__global__ __launch_bounds__(256) void moe_gating3(
    const float* __restrict__ x, const float* __restrict__ gamma,
    const float* __restrict__ beta, const float* __restrict__ keys,
    int* __restrict__ cnt, int4* __restrict__ rmi, float2* __restrict__ rmg,
    unsigned short* __restrict__ xg)
{
  const int b = blockIdx.x, t = threadIdx.x;
  const int w = t >> 6;
  const float4 xv = ((const float4*)(x + (size_t)b * D_))[t];  // d = 4t..4t+3
  float s  = xv.x + xv.y + xv.z + xv.w;
  float sq = xv.x*xv.x + xv.y*xv.y + xv.z*xv.z + xv.w*xv.w;
#pragma unroll
  for (int off = 32; off >= 1; off >>= 1) {
    s  += __shfl_down(s, off);
    sq += __shfl_down(sq, off);
  }
  __shared__ float ssum[4], ssq[4], sstat[2];
  if ((t & 63) == 0) { ssum[w] = s; ssq[w] = sq; }
  __syncthreads();
  if (t == 0) {
    float S = ssum[0] + ssum[1] + ssum[2] + ssum[3];
    float Q = ssq[0] + ssq[1] + ssq[2] + ssq[3];
    float mu  = S * (1.0f / D_);
    float var = Q * (1.0f / D_) - mu * mu;
    sstat[0] = mu; sstat[1] = rsqrtf(var + 1e-5f);
  }
  __syncthreads();
  const float mu = sstat[0], rstd = sstat[1];
  const float4 gv = ((const float4*)gamma)[t];
  const float4 bv = ((const float4*)beta)[t];
  float xn[4] = {(xv.x-mu)*rstd*gv.x+bv.x, (xv.y-mu)*rstd*gv.y+bv.y,
                 (xv.z-mu)*rstd*gv.z+bv.z, (xv.w-mu)*rstd*gv.w+bv.w};
  float acc[E_];
#pragma unroll
  for (int e2 = 0; e2 < E_; ++e2) acc[e2] = 0.f;
#pragma unroll
  for (int j = 0; j < 4; ++j) {
    const int d = 4*t + j;
    const float* kr = keys + (size_t)d * E_;
    float kv[E_];
#pragma unroll
    for (int e2 = 0; e2 < E_; ++e2) kv[e2] = kr[e2];
    float nq = 0.f;
#pragma unroll
    for (int e2 = 0; e2 < E_; ++e2) nq += kv[e2] * kv[e2];
    const float sc = xn[j] / fmaxf(sqrtf(nq), 1e-12f);
#pragma unroll
    for (int e2 = 0; e2 < E_; ++e2) acc[e2] += sc * kv[e2];
  }
#pragma unroll
  for (int off = 1; off < 64; off <<= 1) {
#pragma unroll
    for (int e2 = 0; e2 < E_; ++e2) acc[e2] += __shfl_xor(acc[e2], off);
  }
  __shared__ float wred[4][E_];
  if ((t & 63) == 0) {
#pragma unroll
    for (int e2 = 0; e2 < E_; ++e2) wred[w][e2] = acc[e2];
  }
  __syncthreads();
  __shared__ int sE[2], sP[2];
  if (t == 0) {
    float lg[E_];
#pragma unroll
    for (int e2 = 0; e2 < E_; ++e2)
      lg[e2] = wred[0][e2] + wred[1][e2] + wred[2][e2] + wred[3][e2];
    float v0 = -1e30f; int e0 = 0;
    for (int e2 = 0; e2 < E_; ++e2) { if (lg[e2] > v0) { v0 = lg[e2]; e0 = e2; } }
    float v1 = -1e30f; int e1 = 0;
    for (int e2 = 0; e2 < E_; ++e2) { if (e2 == e0) continue; if (lg[e2] > v1) { v1 = lg[e2]; e1 = e2; } }
    const float g0 = 1.f / (1.f + __expf(v1 - v0));
    const float g1 = 1.f - g0;
    int p0 = atomicAdd(cnt + e0, 1); if (p0 >= CAP) p0 = CAP - 1;
    int p1 = atomicAdd(cnt + e1, 1); if (p1 >= CAP) p1 = CAP - 1;
    rmi[b] = make_int4(e0, p0, e1, p1);
    rmg[b] = make_float2(g0, g1);
    sE[0] = e0; sP[0] = p0;
    sE[1] = e1; sP[1] = p1;
  }
  __syncthreads();
  const uint2 pk = make_uint2(pack2(xv.x, xv.y), pack2(xv.z, xv.w));
#pragma unroll
  for (int i = 0; i < 2; ++i)
    ((uint2*)(xg + ((size_t)sE[i] * CAP + sP[i]) * D_))[t] = pk;
}

// ================= grouped GEMM: dst = [relu](A @ W [+ bias]) -> bf16 =================
// R12 base (best measured) + surgical B-path fix (R13 ablation: B-global = wall):
// 256 thr / 4 waves, tile 128 x 128, Kstep=32, NBUF=2, 3 blocks/CU.
// A bf16 via global_load_lds, chunk-XOR source swizzle (conflict-free b128 reads).
// B fp32: 4 x global_load_dwordx4 / thread (was 16 scalar dwords) -> cvt_pk ->
// 4 x ds_write_b64 into row-major Bs[k][130] bf16 (pad +2). COMP B-frag =
// 16 x ds_read_u16; banks = (k + n/2) mod 32: l4 spans k-offsets {0,8,16,24},
// l15 spans 8 n/2 values -> all 32 banks x 2 lanes = conflict-free.
// vmcnt ledger: {B(p)=4, A(p)=2, B(p+1)=4} -> WAITV(4) drains phase p's ops.
template<int KROW, int KLEN, int WN, int SPLITK, bool RELU>
__global__ void __launch_bounds__(256, 3)
moe_gemm(const unsigned short* __restrict__ Asrc, const float* __restrict__ W,
         const float* __restrict__ bias, const int* __restrict__ cnt,
         unsigned short* __restrict__ d0, unsigned short* __restrict__ d1,
         unsigned short* __restrict__ d2, unsigned short* __restrict__ d3)
{
  constexpr int NPHASE = KLEN / 32;   // even, >= 4
  constexpr int NT = WN / 128;        // N-strips per expert per part
  constexpr int MT = 3;               // 3 x 128-row M-tiles (CAP 384)

  const int bx = blockIdx.x;
  const int xcd = bx & 7;
  int slot = bx >> 3;
  const int mt = slot % MT; slot /= MT;
  const int nt = slot % NT; slot /= NT;
  const int eh = slot & 1;  slot >>= 1;
  const int part = slot;                          // 0..SPLITK-1
  const int e  = (xcd << 1) | eh;                 // 2 experts per XCD
  const int nb = nt * 128;
  const int koff = part * KLEN;
  unsigned short* dst = (part == 0) ? d0 : (part == 1) ? d1 : (part == 2) ? d2 : d3;

  int cntE = cnt[e]; if (cntE > CAP) cntE = CAP;
  if (mt * 128 >= cntE) return;

  const int t = threadIdx.x, w = t >> 6, lane = t & 63;
  const int l15 = lane & 15, l4 = lane >> 4;

  __shared__ __align__(16) unsigned short As[2][128 * 32];   // 8 KiB each
  __shared__ __align__(16) unsigned short Bs[2][32 * 130];   // 8.125 KiB each, padded rows

  asm volatile("s_waitcnt vmcnt(0) lgkmcnt(0)" ::: "memory");

  const unsigned short* Ae = Asrc + (size_t)e * CAP * KROW + (size_t)mt * 128 * KROW + koff;
  const float* We = W + (size_t)e * KROW * WN + (size_t)koff * WN + nb;

  // A staging: chunk c = i*256+t (i=0,1); row = c>>2 (0..127); src chunk = (c&3)^((row>>1)&3)
  const unsigned short *srcA0, *srcA1;
  {
    const int c0 = t,        r0 = c0 >> 2;
    const int c1 = t + 256,  r1 = c1 >> 2;
    srcA0 = Ae + (size_t)r0 * KROW + ((c0 & 3) ^ ((r0 >> 1) & 3)) * 8;
    srcA1 = Ae + (size_t)r1 * KROW + ((c1 & 3) ^ ((r1 >> 1) & 3)) * 8;
  }
  // B load: thread t -> k-row bk = t>>3; 4 dwordx4 at cols (t&7)*4 + i*32
  const int bk = t >> 3, bc = (t & 7) * 4;
  const float* srcB = We + (size_t)bk * WN + bc;
  // B LDS write byte offsets: Bs[k][130] bf16 rows (260 B); b64 at k*260 + c*2
  const int bwo = bk * 260 + bc * 2;              // + i*64 per chunk

  f32x4 R0[4], R1[4];   // two B reg buffers (static indexing only)

#define ISSUE_A(p, BUF) do {                                                \
    const int ko_ = (p) * 32;                                               \
    GLL16(srcA0 + ko_, &As[BUF][(0 * 256 + w * 64) * 8]);                   \
    GLL16(srcA1 + ko_, &As[BUF][(1 * 256 + w * 64) * 8]);                   \
  } while (0)

#define ISSUE_B(p, Rv) do {                                                 \
    const float* bp_ = srcB + (size_t)(p) * 32 * WN;                        \
    _Pragma("unroll")                                                       \
    for (int i = 0; i < 4; ++i)                                             \
      Rv[i] = *(const f32x4*)(bp_ + i * 32);                                \
  } while (0)

#define WRITE(Rv, BUF) do {                                                 \
    _Pragma("unroll")                                                       \
    for (int i = 0; i < 4; ++i) {                                           \
      uint2 q_;                                                             \
      q_.x = pack2(Rv[i][0], Rv[i][1]);                                     \
      q_.y = pack2(Rv[i][2], Rv[i][3]);                                     \
      *(uint2*)((char*)&Bs[BUF][0] + bwo + i * 64) = q_;                    \
    }                                                                       \
  } while (0)

  f32x4 acc[8][2];
#pragma unroll
  for (int rf = 0; rf < 8; ++rf) { acc[rf][0] = f32x4{0,0,0,0}; acc[rf][1] = f32x4{0,0,0,0}; }

  const int swA = (l15 >> 1) & 3;             // A-read chunk XOR
  const int mrow0 = mt * 128;

#define COMP(BUF) do {                                                      \
    union { unsigned short s[8]; bf16x8 v; } BB[2];                         \
    _Pragma("unroll")                                                       \
    for (int cf = 0; cf < 2; ++cf) {                                        \
      const int n_ = w * 32 + cf * 16 + l15;                                \
      _Pragma("unroll")                                                     \
      for (int j = 0; j < 8; ++j)                                           \
        BB[cf].s[j] = Bs[BUF][(l4 * 8 + j) * 130 + n_];                     \
    }                                                                       \
    __builtin_amdgcn_s_setprio(1);                                          \
    _Pragma("unroll")                                                       \
    for (int rf = 0; rf < 8; ++rf) {                                        \
      if (mrow0 + rf * 16 < cntE) {                                         \
        const bf16x8 a = *(const bf16x8*)&As[BUF][((rf * 16 + l15) * 4 + (l4 ^ swA)) * 8]; \
        acc[rf][0] = __builtin_amdgcn_mfma_f32_16x16x32_bf16(a, BB[0].v, acc[rf][0], 0,0,0); \
        acc[rf][1] = __builtin_amdgcn_mfma_f32_16x16x32_bf16(a, BB[1].v, acc[rf][1], 0,0,0); \
      }                                                                     \
    }                                                                       \
    __builtin_amdgcn_s_setprio(0);                                          \
  } while (0)

  // prologue: FIFO order A(0) | B(0) | B(1)
  ISSUE_A(0, 0); MEMBAR();
  ISSUE_B(0, R0); MEMBAR();
  ISSUE_B(1, R1);
#pragma unroll 1
  for (int p = 0; p < NPHASE; p += 2) {
    // ---- phase p: bufs 0, B regs R0
    if (p + 1 < NPHASE) { WAITV(4); } else { WAITV(0); }
    WRITE(R0, 0);
    if (p + 1 < NPHASE) { ISSUE_A(p + 1, 1); }
    MEMBAR();
    if (p + 2 < NPHASE) { ISSUE_B(p + 2, R0); }
    WAITL(); BAR();
    COMP(0);
    BAR();
    // ---- phase p+1: bufs 1, B regs R1
    if (p + 1 < NPHASE) {
      if (p + 2 < NPHASE) { WAITV(4); } else { WAITV(0); }
      WRITE(R1, 1);
      if (p + 2 < NPHASE) { ISSUE_A(p + 2, 0); }
      MEMBAR();
      if (p + 3 < NPHASE) { ISSUE_B(p + 3, R1); }
      WAITL(); BAR();
      COMP(1);
      BAR();
    }
  }
#undef ISSUE_A
#undef ISSUE_B
#undef WRITE
#undef COMP

  // epilogue: [relu(acc+bias)] -> dst bf16, 4-col packs via shfl
  unsigned short* dbase = dst + (size_t)e * CAP * WN + nb + w * 32;
#pragma unroll
  for (int rf = 0; rf < 8; ++rf) {
    if (mrow0 + rf * 16 >= cntE && rf > 0) continue;   // wave-uniform skip
#pragma unroll
    for (int cf = 0; cf < 2; ++cf) {
      float bv = 0.f;
      if constexpr (RELU) bv = bias[e * WN + nb + w * 32 + cf * 16 + l15];
#pragma unroll
      for (int r = 0; r < 4; ++r) {
        const int row = mrow0 + rf * 16 + l4 * 4 + r;
        float v = acc[rf][cf][r];
        if constexpr (RELU) v = fmaxf(v + bv, 0.f);
        const unsigned u01 = pack2(v, __shfl_xor(v, 1));
        const float uo = __shfl_xor(__uint_as_float(u01), 2);
        if ((l15 & 3) == 0)
          *(uint2*)(dbase + (size_t)row * WN + cf * 16 + l15) =
              make_uint2(u01, __float_as_uint(uo));
      }
    }
  }
}

// ================= combine: out[b] = g0*(sum eoP[e0]+b2) + g1*(sum eoP[e1]+b2) ============
__global__ __launch_bounds__(256) void moe_comb(
    const unsigned short* __restrict__ p0, const unsigned short* __restrict__ p1,
    const unsigned short* __restrict__ p2, const unsigned short* __restrict__ p3,
    const float* __restrict__ b2, const int4* __restrict__ rmi,
    const float2* __restrict__ rmg, float* __restrict__ out)
{
  const int b = blockIdx.x, t = threadIdx.x;
  const int4 m = rmi[b];
  const float2 g = rmg[b];
  const int c = t * 4;
  const size_t offA = ((size_t)m.x * CAP + m.y) * D_ + c;
  const size_t offB = ((size_t)m.z * CAP + m.w) * D_ + c;
  float a0, a1, a2, a3, c0, c1, c2, c3;
  {
    const uint2 ua = *(const uint2*)(p0 + offA);
    const uint2 ub = *(const uint2*)(p0 + offB);
    a0 = bflo(ua.x); a1 = bfhi(ua.x); a2 = bflo(ua.y); a3 = bfhi(ua.y);
    c0 = bflo(ub.x); c1 = bfhi(ub.x); c2 = bflo(ub.y); c3 = bfhi(ub.y);
  }
  const unsigned short* parts[3] = { p1, p2, p3 };
#pragma unroll
  for (int i = 0; i < 3; ++i) {
    if (parts[i] != nullptr) {
      const uint2 ua = *(const uint2*)(parts[i] + offA);
      const uint2 ub = *(const uint2*)(parts[i] + offB);
      a0 += bflo(ua.x); a1 += bfhi(ua.x); a2 += bflo(ua.y); a3 += bfhi(ua.y);
      c0 += bflo(ub.x); c1 += bfhi(ub.x); c2 += bflo(ub.y); c3 += bfhi(ub.y);
    }
  }
  const float4 b2a = *(const float4*)(b2 + (size_t)m.x * D_ + c);
  const float4 b2b = *(const float4*)(b2 + (size_t)m.z * D_ + c);
  float4 o;
  o.x = g.x * (a0 + b2a.x) + g.y * (c0 + b2b.x);
  o.y = g.x * (a1 + b2a.y) + g.y * (c1 + b2b.y);
  o.z = g.x * (a2 + b2a.z) + g.y * (c2 + b2b.z);
  o.w = g.x * (a3 + b2a.w) + g.y * (c3 + b2b.w);
  *(float4*)(out + (size_t)b * D_ + c) = o;
}

// ======================= launch =======================
extern "C" void kernel_launch(void* const* d_in, const int* in_sizes, int n_in,
                              void* d_out, int out_size, void* d_ws, size_t ws_size,
                              hipStream_t stream) {
  const float* x     = (const float*)d_in[0];
  const float* gamma = (const float*)d_in[1];
  const float* beta  = (const float*)d_in[2];
  const float* keys  = (const float*)d_in[3];
  const float* W1    = (const float*)d_in[4];
  const float* b1    = (const float*)d_in[5];
  const float* W2    = (const float*)d_in[6];
  const float* b2    = (const float*)d_in[7];
  float* out = (float*)d_out;

  char* ws = (char*)d_ws;
  const size_t OFF_RMI = 256;
  const size_t OFF_RMG = OFF_RMI + (size_t)B_ * 16;
  const size_t OFF_XG  = OFF_RMG + (size_t)B_ * 8;
  const size_t EO_SZ   = (size_t)E_ * CAP * D_ * 2;            // 12 MiB
  const size_t OFF_HW  = OFF_XG + EO_SZ;                       // xg / eo part0 overlay
  const size_t HW_SZ   = (size_t)E_ * CAP * H_ * 2;            // 48 MiB
  const size_t OFF_EO1 = OFF_HW + HW_SZ;
  const size_t NEED2   = OFF_EO1 + EO_SZ;                      // ~72.1 MiB
  const size_t NEED4   = OFF_EO1 + 3 * EO_SZ;                  // ~96.1 MiB (proven)

  int*    cnt = (int*)ws;
  int4*   rmi = (int4*)(ws + OFF_RMI);
  float2* rmg = (float2*)(ws + OFF_RMG);
  unsigned short* xg  = (unsigned short*)(ws + OFF_XG);
  unsigned short* eo0 = xg;                                    // xg dead after GEMM1
  unsigned short* hws = (unsigned short*)(ws + OFF_HW);

  moe_zero<<<1, 64, 0, stream>>>(cnt);
  moe_gating3<<<B_, 256, 0, stream>>>(x, gamma, beta, keys, cnt, rmi, rmg, xg);

  // GEMM1: tile 128x128, grid 1536 (8 xcd x 3 mt x 32 nt x 2 eh), 3 blocks/CU
  moe_gemm<D_, D_, H_, 1, true><<<1536, 256, 0, stream>>>(
      xg, W1, b1, cnt, hws, nullptr, nullptr, nullptr);

  if (ws_size >= NEED4) {
    // GEMM2: tile 128x128, split-K=4, grid 1536
    unsigned short* eo1 = (unsigned short*)(ws + OFF_EO1);
    unsigned short* eo2 = (unsigned short*)(ws + OFF_EO1 + EO_SZ);
    unsigned short* eo3 = (unsigned short*)(ws + OFF_EO1 + 2 * EO_SZ);
    moe_gemm<H_, H_ / 4, D_, 4, false><<<1536, 256, 0, stream>>>(
        hws, W2, nullptr, cnt, eo0, eo1, eo2, eo3);
    moe_comb<<<B_, 256, 0, stream>>>(eo0, eo1, eo2, eo3, b2, rmi, rmg, out);
  } else if (ws_size >= NEED2) {
    // GEMM2: split-K=2, grid 768
    unsigned short* eo1 = (unsigned short*)(ws + OFF_EO1);
    moe_gemm<H_, H_ / 2, D_, 2, false><<<768, 256, 0, stream>>>(
        hws, W2, nullptr, cnt, eo0, eo1, nullptr, nullptr);
    moe_comb<<<B_, 256, 0, stream>>>(eo0, eo1, nullptr, nullptr, b2, rmi, rmg, out);
  } else {
    // GEMM2: no split, grid 384
    moe_gemm<H_, H_, D_, 1, false><<<384, 256, 0, stream>>>(
        hws, W2, nullptr, cnt, eo0, nullptr, nullptr, nullptr);
    moe_comb<<<B_, 256, 0, stream>>>(eo0, nullptr, nullptr, nullptr, b2, rmi, rmg, out);
  }
}